// Round 13
// baseline (75.542 us; speedup 1.0000x reference)
//
#include <hip/hip_runtime.h>
#include <math.h>

// Rotated 3D IoU loss — round 13: 2-wide SoA ("f2") version of R10.
// R12 post-mortem: 2 items/thread via two sequential inlined calls gave only
// +1.4us — ILP x2 halves wave count (1953 waves = 1.9/SIMD) and the machine
// scheduler does NOT interleave two ~600-inst chains on its own. This round
// forces pairing at IR level: every value is f2{itemA,itemB}, so each source
// op emits two adjacent independent VALU insts — guaranteed dual-chain ILP
// through the sort's dependency chain.
// Semantics = literal emulation of the reference (incl. its u = -den_u/num
// "backward-extension" intersection mask — verified numerically in R6).

#define RCP(x) __builtin_amdgcn_rcpf(x)

struct f2 { float a, b; };
struct b2 { bool a, b; };
struct i2 { int a, b; };
struct u2 { unsigned a, b; };

__device__ __forceinline__ f2 operator+(f2 p, f2 q) { return {p.a + q.a, p.b + q.b}; }
__device__ __forceinline__ f2 operator-(f2 p, f2 q) { return {p.a - q.a, p.b - q.b}; }
__device__ __forceinline__ f2 operator*(f2 p, f2 q) { return {p.a * q.a, p.b * q.b}; }
__device__ __forceinline__ f2 operator*(float s, f2 q) { return {s * q.a, s * q.b}; }
__device__ __forceinline__ f2 operator-(f2 p) { return {-p.a, -p.b}; }
__device__ __forceinline__ f2 rcp2(f2 p) { return {RCP(p.a), RCP(p.b)}; }
__device__ __forceinline__ f2 fmin2(f2 p, f2 q) { return {fminf(p.a, q.a), fminf(p.b, q.b)}; }
__device__ __forceinline__ f2 fmax2(f2 p, f2 q) { return {fmaxf(p.a, q.a), fmaxf(p.b, q.b)}; }
__device__ __forceinline__ f2 fabs2(f2 p) { return {fabsf(p.a), fabsf(p.b)}; }
__device__ __forceinline__ f2 cps2(f2 p, f2 s) { return {copysignf(p.a, s.a), copysignf(p.b, s.b)}; }
__device__ __forceinline__ f2 sin2(f2 p) { return {__sinf(p.a), __sinf(p.b)}; }
__device__ __forceinline__ f2 cos2(f2 p) { return {__cosf(p.a), __cosf(p.b)}; }
__device__ __forceinline__ f2 log2f2(f2 p) { return {__logf(p.a), __logf(p.b)}; }
__device__ __forceinline__ b2 lt2(f2 p, f2 q) { return {p.a < q.a, p.b < q.b}; }
__device__ __forceinline__ b2 gt2(f2 p, f2 q) { return {p.a > q.a, p.b > q.b}; }
__device__ __forceinline__ b2 and2(b2 p, b2 q) { return {p.a && q.a, p.b && q.b}; }
__device__ __forceinline__ f2 sel(b2 c, f2 p, f2 q) { return {c.a ? p.a : q.a, c.b ? p.b : q.b}; }
__device__ __forceinline__ u2 selu(b2 c, u2 p, u2 q) { return {c.a ? p.a : q.a, c.b ? p.b : q.b}; }
__device__ __forceinline__ f2 i2f(i2 p) { return {(float)p.a, (float)p.b}; }

__device__ __forceinline__ u2 pack2(f2 x, f2 y) {
    return {(__float_as_uint(x.a) & 0xFFFF0000u) | (__float_as_uint(y.a) >> 16),
            (__float_as_uint(x.b) & 0xFFFF0000u) | (__float_as_uint(y.b) >> 16)};
}
__device__ __forceinline__ f2 unpx(u2 p) {
    return {__uint_as_float(p.a & 0xFFFF0000u), __uint_as_float(p.b & 0xFFFF0000u)};
}
__device__ __forceinline__ f2 unpy(u2 p) {
    return {__uint_as_float(p.a << 16), __uint_as_float(p.b << 16)};
}

__global__ __launch_bounds__(256, 2) void riou_loss_kernel(
    const float* __restrict__ pred, const float* __restrict__ tgt,
    const float* __restrict__ wgt, float* __restrict__ ws, int n)
{
    const f2 zero = {0.f, 0.f}, half = {0.5f, 0.5f}, onev = {1.f, 1.f};
    const f2 bigv = {1e6f, 1e6f}, big5 = {5e5f, 5e5f}, tiny = {1e-38f, 1e-38f};
    const f2 htv = {0.5f + 1e-6f, 0.5f + 1e-6f};

    int t0 = blockIdx.x * 512 + threadIdx.x;
    int t1 = t0 + 256;
    int ia = min(t0, n - 1), ib = min(t1, n - 1);
    f2 wg = {(t0 < n) ? wgt[ia] : 0.0f, (t1 < n) ? wgt[ib] : 0.0f};

    const float* pA = pred + 7 * ia;  const float* pB = pred + 7 * ib;
    const float* qA = tgt + 7 * ia;   const float* qB = tgt + 7 * ib;
    f2 p0 = {pA[0], pB[0]}, p1 = {pA[1], pB[1]}, p2 = {pA[2], pB[2]}, p3 = {pA[3], pB[3]};
    f2 p4 = {pA[4], pB[4]}, p5 = {pA[5], pB[5]}, p6 = {pA[6], pB[6]};
    f2 q0 = {qA[0], qB[0]}, q1 = {qA[1], qB[1]}, q2 = {qA[2], qB[2]}, q3 = {qA[3], qB[3]};
    f2 q4 = {qA[4], qB[4]}, q5 = {qA[5], qB[5]}, q6 = {qA[6], qB[6]};

    // ---- decode_fcos_obb (loc = 0) ----
    f2 w1 = p0 + p3, l1 = p1 + p4, h1 = p2 + p5;
    f2 oz1 = 0.5f * (p5 - p2);
    f2 ox1 = 0.5f * (p3 - p0), oy1 = 0.5f * (p4 - p1);
    f2 sA = sin2(p6), cA = cos2(p6);
    f2 cx1 = ox1 * cA - oy1 * sA, cy1 = ox1 * sA + oy1 * cA;

    f2 w2 = q0 + q3, l2 = q1 + q4, h2 = q2 + q5;
    f2 oz2 = 0.5f * (q5 - q2);
    f2 ox2 = 0.5f * (q3 - q0), oy2 = 0.5f * (q4 - q1);
    f2 sB = sin2(q6), cB = cos2(q6);
    f2 cx2 = ox2 * cB - oy2 * sB, cy2 = ox2 * sB + oy2 * cB;

    f2 vol1 = w1 * l1 * h1, vol2 = w2 * l2 * h2;
    f2 zo = fmax2(fmin2(oz1 + 0.5f * h1, oz2 + 0.5f * h2) -
                  fmax2(oz1 - 0.5f * h1, oz2 - 0.5f * h2), zero);

    // ---- corners: signs (+,+),(-,+),(-,-),(+,-) of (w/2, l/2), rotated ----
    f2 hw1 = 0.5f * w1, hl1 = 0.5f * l1;
    f2 c1x0 = hw1 * cA - hl1 * sA + cx1, c1y0 = hw1 * sA + hl1 * cA + cy1;
    f2 c1x1 = zero - hw1 * cA - hl1 * sA + cx1, c1y1 = zero - hw1 * sA + hl1 * cA + cy1;
    f2 c1x2 = zero - hw1 * cA + hl1 * sA + cx1, c1y2 = zero - hw1 * sA - hl1 * cA + cy1;
    f2 c1x3 = hw1 * cA + hl1 * sA + cx1, c1y3 = hw1 * sA - hl1 * cA + cy1;
    f2 hw2 = 0.5f * w2, hl2 = 0.5f * l2;
    f2 c2x0 = hw2 * cB - hl2 * sB + cx2, c2y0 = hw2 * sB + hl2 * cB + cy2;
    f2 c2x1 = zero - hw2 * cB - hl2 * sB + cx2, c2y1 = zero - hw2 * sB + hl2 * cB + cy2;
    f2 c2x2 = zero - hw2 * cB + hl2 * sB + cx2, c2y2 = zero - hw2 * sB - hl2 * cB + cy2;
    f2 c2x3 = hw2 * cB + hl2 * sB + cx2, c2y3 = hw2 * sB - hl2 * cB + cy2;

    f2 sumx = zero, sumy = zero;
    i2 nv = {0, 0};
#define ACC(M, X, Y) { sumx = sumx + sel(M, X, zero); sumy = sumy + sel(M, Y, zero); \
        nv.a += (M).a; nv.b += (M).b; }

    // ---- point-in-box masks; x in (-tol,1+tol) <=> |x-0.5| < 0.5+tol ----
    f2 abxB = c2x1 - c2x0, abyB = c2y1 - c2y0;
    f2 adxB = c2x3 - c2x0, adyB = c2y3 - c2y0;
    f2 rabB = rcp2(abxB * abxB + abyB * abyB);
    f2 radB = rcp2(adxB * adxB + adyB * adyB);
#define PIB_B(MX, MY, M) { f2 amx = (MX) - c2x0, amy = (MY) - c2y0; \
        f2 pab = (abxB * amx + abyB * amy) * rabB; \
        f2 pdd = (adxB * amx + adyB * amy) * radB; \
        M = and2(lt2(fabs2(pab - half), htv), lt2(fabs2(pdd - half), htv)); }
    b2 mA0, mA1, mA2, mA3;
    PIB_B(c1x0, c1y0, mA0) PIB_B(c1x1, c1y1, mA1)
    PIB_B(c1x2, c1y2, mA2) PIB_B(c1x3, c1y3, mA3)
    ACC(mA0, c1x0, c1y0) ACC(mA1, c1x1, c1y1) ACC(mA2, c1x2, c1y2) ACC(mA3, c1x3, c1y3)
    f2 abxA = c1x1 - c1x0, abyA = c1y1 - c1y0;
    f2 adxA = c1x3 - c1x0, adyA = c1y3 - c1y0;
    f2 rabA = rcp2(abxA * abxA + abyA * abyA);
    f2 radA = rcp2(adxA * adxA + adyA * adyA);
#define PIB_A(MX, MY, M) { f2 amx = (MX) - c1x0, amy = (MY) - c1y0; \
        f2 pab = (abxA * amx + abyA * amy) * rabA; \
        f2 pdd = (adxA * amx + adyA * amy) * radA; \
        M = and2(lt2(fabs2(pab - half), htv), lt2(fabs2(pdd - half), htv)); }
    b2 mB0, mB1, mB2, mB3;
    PIB_A(c2x0, c2y0, mB0) PIB_A(c2x1, c2y1, mB1)
    PIB_A(c2x2, c2y2, mB2) PIB_A(c2x3, c2y3, mB3)
    ACC(mB0, c2x0, c2y0) ACC(mB1, c2x1, c2y1) ACC(mB2, c2x2, c2y2) ACC(mB3, c2x3, c2y3)

    // ---- edge-edge "intersections", reference's exact (buggy-u) mask ----
#define ISECT(X1, Y1, X2, Y2, X3, Y3, X4, Y4, PX, PY, M) { \
        f2 ex = (X2) - (X1), ey = (Y2) - (Y1); \
        f2 fx = (X4) - (X3), fy = (Y4) - (Y3); \
        f2 gx = (X1) - (X3), gy = (Y1) - (Y3); \
        f2 num = fy * ex - fx * ey; \
        f2 dt_ = fx * gy - fy * gx; \
        f2 du_ = ex * gy - ey * gx; \
        f2 rr = rcp2(num); \
        f2 tt = dt_ * rr, uu = zero - du_ * rr; \
        M = and2(lt2(fabs2(tt - half), half), lt2(fabs2(uu - half), half)); \
        PX = (X1) + tt * ex; PY = (Y1) + tt * ey; }
#define SITEM(PX, PY, M, OX0, OY0, OX1, OY1, CNT) { \
        b2 tk0 = {(M).a && (CNT).a == 0, (M).b && (CNT).b == 0}; \
        b2 tk1 = {(M).a && (CNT).a == 1, (M).b && (CNT).b == 1}; \
        OX0 = sel(tk0, PX, OX0); OY0 = sel(tk0, PY, OY0); \
        OX1 = sel(tk1, PX, OX1); OY1 = sel(tk1, PY, OY1); \
        (CNT).a += (M).a; (CNT).b += (M).b; }
#define EDGE_GROUP(X1, Y1, X2, Y2, EX0, EY0, EX1, EY1) { \
        i2 gc = {0, 0}; f2 px, py; b2 mm; \
        ISECT(X1, Y1, X2, Y2, c2x0, c2y0, c2x1, c2y1, px, py, mm) \
        ACC(mm, px, py) SITEM(px, py, mm, EX0, EY0, EX1, EY1, gc) \
        ISECT(X1, Y1, X2, Y2, c2x1, c2y1, c2x2, c2y2, px, py, mm) \
        ACC(mm, px, py) SITEM(px, py, mm, EX0, EY0, EX1, EY1, gc) \
        ISECT(X1, Y1, X2, Y2, c2x2, c2y2, c2x3, c2y3, px, py, mm) \
        ACC(mm, px, py) SITEM(px, py, mm, EX0, EY0, EX1, EY1, gc) \
        ISECT(X1, Y1, X2, Y2, c2x3, c2y3, c2x0, c2y0, px, py, mm) \
        ACC(mm, px, py) SITEM(px, py, mm, EX0, EY0, EX1, EY1, gc) }

    f2 vx8 = zero, vy8 = zero, vx9 = zero, vy9 = zero;
    f2 vx10 = zero, vy10 = zero, vx11 = zero, vy11 = zero;
    f2 vx12 = zero, vy12 = zero, vx13 = zero, vy13 = zero;
    f2 vx14 = zero, vy14 = zero, vx15 = zero, vy15 = zero;
    i2 nv8b = nv;
    EDGE_GROUP(c1x0, c1y0, c1x1, c1y1, vx8, vy8, vx9, vy9)
    i2 nv10b = nv;
    EDGE_GROUP(c1x1, c1y1, c1x2, c1y2, vx10, vy10, vx11, vy11)
    i2 nv12b = nv;
    EDGE_GROUP(c1x2, c1y2, c1x3, c1y3, vx12, vy12, vx13, vy13)
    i2 nv14b = nv;
    EDGE_GROUP(c1x3, c1y3, c1x0, c1y0, vx14, vy14, vx15, vy15)
    b2 m8  = {nv10b.a - nv8b.a > 0, nv10b.b - nv8b.b > 0};
    b2 m9  = {nv10b.a - nv8b.a > 1, nv10b.b - nv8b.b > 1};
    b2 m10 = {nv12b.a - nv10b.a > 0, nv12b.b - nv10b.b > 0};
    b2 m11 = {nv12b.a - nv10b.a > 1, nv12b.b - nv10b.b > 1};
    b2 m12 = {nv14b.a - nv12b.a > 0, nv14b.b - nv12b.b > 0};
    b2 m13 = {nv14b.a - nv12b.a > 1, nv14b.b - nv12b.b > 1};
    b2 m14 = {nv.a - nv14b.a > 0, nv.b - nv14b.b > 0};
    b2 m15 = {nv.a - nv14b.a > 1, nv.b - nv14b.b > 1};

    f2 vx0 = c1x0, vy0 = c1y0, vx1 = c1x1, vy1 = c1y1;
    f2 vx2 = c1x2, vy2 = c1y2, vx3 = c1x3, vy3 = c1y3;
    f2 vx4 = c2x0, vy4 = c2y0, vx5 = c2x1, vy5 = c2y1;
    f2 vx6 = c2x2, vy6 = c2y2, vx7 = c2x3, vy7 = c2y3;
    b2 m0 = mA0, m1 = mA1, m2 = mA2, m3 = mA3;
    b2 m4 = mB0, m5 = mB1, m6 = mB2, m7 = mB3;

    // ---- center; branch-free diamond key (monotone in atan2, verified) ----
    f2 inv_nv = rcp2(fmax2(i2f(nv), onev));
    f2 mx_ = sumx * inv_nv, my_ = sumy * inv_nv;
    f2 ang0, ang1, ang2, ang3, ang4, ang5, ang6, ang7;
    f2 ang8, ang9, ang10, ang11, ang12, ang13, ang14, ang15;
    u2 pk0, pk1, pk2, pk3, pk4, pk5, pk6, pk7;
    u2 pk8, pk9, pk10, pk11, pk12, pk13, pk14, pk15;
#define ANGPACK(K) { f2 xc = vx##K - mx_, yc = vy##K - my_; \
        f2 tt = xc * rcp2(fmax2(fabs2(xc) + fabs2(yc), tiny)); \
        f2 key = cps2(onev - tt, yc); \
        ang##K = sel(m##K, key, bigv); \
        pk##K = pack2(xc, yc); }
    ANGPACK(0) ANGPACK(1) ANGPACK(2) ANGPACK(3)
    ANGPACK(4) ANGPACK(5) ANGPACK(6) ANGPACK(7)
    ANGPACK(8) ANGPACK(9) ANGPACK(10) ANGPACK(11)
    ANGPACK(12) ANGPACK(13) ANGPACK(14) ANGPACK(15)

    // ---- Batcher odd-even mergesort, 16 elems, 63 CEs, dual-lane ----
#define CE(A, B) { b2 sw = gt2(ang##A, ang##B); \
        f2 mn = fmin2(ang##A, ang##B), mx2 = fmax2(ang##A, ang##B); \
        ang##A = mn; ang##B = mx2; \
        u2 ta = pk##A; pk##A = selu(sw, pk##B, pk##A); pk##B = selu(sw, ta, pk##B); }
    CE(0,1) CE(2,3) CE(4,5) CE(6,7) CE(8,9) CE(10,11) CE(12,13) CE(14,15)
    CE(0,2) CE(1,3) CE(4,6) CE(5,7) CE(8,10) CE(9,11) CE(12,14) CE(13,15)
    CE(1,2) CE(5,6) CE(9,10) CE(13,14)
    CE(0,4) CE(1,5) CE(2,6) CE(3,7) CE(8,12) CE(9,13) CE(10,14) CE(11,15)
    CE(2,4) CE(3,5) CE(10,12) CE(11,13)
    CE(1,2) CE(3,4) CE(5,6) CE(9,10) CE(11,12) CE(13,14)
    CE(0,8) CE(1,9) CE(2,10) CE(3,11) CE(4,12) CE(5,13) CE(6,14) CE(7,15)
    CE(4,8) CE(5,9) CE(6,10) CE(7,11)
    CE(2,4) CE(3,5) CE(6,8) CE(7,9) CE(10,12) CE(11,13)
    CE(1,2) CE(3,4) CE(5,6) CE(7,8) CE(9,10) CE(11,12) CE(13,14)

    // ---- ref padding: invalid slots (key 1e6) sorted last ----
#define PAD(K) { b2 pc = gt2(ang##K, big5); pk##K = selu(pc, pk0, pk##K); }
    PAD(1) PAD(2) PAD(3) PAD(4) PAD(5) PAD(6) PAD(7) PAD(8)
    PAD(9) PAD(10) PAD(11) PAD(12) PAD(13) PAD(14) PAD(15)

    // ---- unpack + cyclic shoelace ----
#define UPX(K) f2 ux##K = unpx(pk##K); f2 uy##K = unpy(pk##K);
    UPX(0) UPX(1) UPX(2) UPX(3) UPX(4) UPX(5) UPX(6) UPX(7)
    UPX(8) UPX(9) UPX(10) UPX(11) UPX(12) UPX(13) UPX(14) UPX(15)
    f2 cs = zero;
#define SHOE(A, B) cs = cs + ux##A * uy##B - uy##A * ux##B;
    SHOE(0,1) SHOE(1,2) SHOE(2,3) SHOE(3,4) SHOE(4,5) SHOE(5,6) SHOE(6,7) SHOE(7,8)
    SHOE(8,9) SHOE(9,10) SHOE(10,11) SHOE(11,12) SHOE(12,13) SHOE(13,14) SHOE(14,15) SHOE(15,0)
    f2 inter = 0.5f * fabs2(cs);

    // ---- loss (iou2d*u2 cancels u2 -> inter3d = inter*zo) ----
    f2 inter3d = inter * zo;
    f2 u3d = vol1 + vol2 - inter3d;
    f2 iouf = (inter3d + onev) * rcp2(u3d + onev);
    f2 lo2 = (zero - log2f2(iouf)) * wg;
    float loss = lo2.a + lo2.b;

    // ---- block reduction -> ONE partial-sum store per block ----
#pragma unroll
    for (int off = 32; off > 0; off >>= 1)
        loss += __shfl_down(loss, off, 64);
    __shared__ float wsum[4];
    int lane = threadIdx.x & 63, wid = threadIdx.x >> 6;
    if (lane == 0) wsum[wid] = loss;
    __syncthreads();
    if (threadIdx.x == 0)
        ws[blockIdx.x] = wsum[0] + wsum[1] + wsum[2] + wsum[3];
}

__global__ __launch_bounds__(256) void riou_reduce_kernel(
    const float* __restrict__ ws, float* __restrict__ out, int nb)
{
    float s = 0.0f;
    for (int t = threadIdx.x; t < nb; t += 256) s += ws[t];
#pragma unroll
    for (int off = 32; off > 0; off >>= 1)
        s += __shfl_down(s, off, 64);
    __shared__ float wsum[4];
    int lane = threadIdx.x & 63, wid = threadIdx.x >> 6;
    if (lane == 0) wsum[wid] = s;
    __syncthreads();
    if (threadIdx.x == 0)
        out[0] = wsum[0] + wsum[1] + wsum[2] + wsum[3];
}

extern "C" void kernel_launch(void* const* d_in, const int* in_sizes, int n_in,
                              void* d_out, int out_size, void* d_ws, size_t ws_size,
                              hipStream_t stream) {
    const float* pred = (const float*)d_in[0];
    const float* tgt  = (const float*)d_in[1];
    const float* wgt  = (const float*)d_in[2];
    float* out = (float*)d_out;
    float* ws  = (float*)d_ws;
    int n = in_sizes[2];

    int grid = (n + 511) / 512;   // 489 for n=250000
    riou_loss_kernel<<<grid, 256, 0, stream>>>(pred, tgt, wgt, ws, n);
    riou_reduce_kernel<<<1, 256, 0, stream>>>(ws, out, grid);
}